// Round 1
// baseline (318.869 us; speedup 1.0000x reference)
//
#include <hip/hip_runtime.h>
#include <hip/hip_bf16.h>
#include <math.h>

#define BS 32
#define NQ 900
#define NC 91
#define NT 30
#define NJ (BS*NT)            // 960
#define C3_SZ ((size_t)BS*NQ*NJ)

// ---------------- Cost matrix kernel ----------------
// one block per (b,q) row; 256 threads stream the 960 target columns.
__global__ __launch_bounds__(256) void cost_kernel(
    const float* __restrict__ logits,   // (BS,NQ,NC)
    const float* __restrict__ pboxes,   // (BS,NQ,4)
    const int*   __restrict__ tlabels,  // (NJ)
    const float* __restrict__ tboxes,   // (NJ,4)
    float* __restrict__ out)            // (BS,NQ,NJ)
{
    int row = blockIdx.x;               // 0..28799 == b*NQ+q
    const float* lrow = logits + (size_t)row * NC;
    __shared__ float llog[NC];
    __shared__ float sh_mx, sh_rs;
    int tid = threadIdx.x;
    if (tid < NC) llog[tid] = lrow[tid];
    __syncthreads();
    if (tid < 64) {
        float a = (tid < NC) ? llog[tid] : -INFINITY;
        float c = (tid + 64 < NC) ? llog[tid + 64] : -INFINITY;
        float m = fmaxf(a, c);
        for (int off = 32; off; off >>= 1) m = fmaxf(m, __shfl_xor(m, off));
        float s = 0.f;
        if (tid < NC)      s += expf(a - m);
        if (tid + 64 < NC) s += expf(c - m);
        for (int off = 32; off; off >>= 1) s += __shfl_xor(s, off);
        if (tid == 0) { sh_mx = m; sh_rs = 1.0f / s; }
    }
    __syncthreads();
    float mx = sh_mx, rs = sh_rs;
    float pcx = pboxes[(size_t)row*4+0], pcy = pboxes[(size_t)row*4+1];
    float pw  = pboxes[(size_t)row*4+2], ph  = pboxes[(size_t)row*4+3];
    float px0 = pcx - 0.5f*pw, py0 = pcy - 0.5f*ph;
    float px1 = pcx + 0.5f*pw, py1 = pcy + 0.5f*ph;
    float area_a = (px1 - px0) * (py1 - py0);
    float* orow = out + (size_t)row * NJ;
    for (int j = tid; j < NJ; j += 256) {
        int tl = tlabels[j];
        float prob = expf(llog[tl] - mx) * rs;
        float cost_class = 1.0f - prob;
        float tcx = tboxes[j*4+0], tcy = tboxes[j*4+1];
        float tw  = tboxes[j*4+2], th  = tboxes[j*4+3];
        float cost_bbox = fabsf(pcx-tcx) + fabsf(pcy-tcy) + fabsf(pw-tw) + fabsf(ph-th);
        float tx0 = tcx - 0.5f*tw, ty0 = tcy - 0.5f*th;
        float tx1 = tcx + 0.5f*tw, ty1 = tcy + 0.5f*th;
        float area_b = (tx1 - tx0) * (ty1 - ty0);
        float ix0 = fmaxf(px0, tx0), iy0 = fmaxf(py0, ty0);
        float ix1 = fminf(px1, tx1), iy1 = fminf(py1, ty1);
        float iw = fmaxf(ix1 - ix0, 0.f), ih = fmaxf(iy1 - iy0, 0.f);
        float inter = iw * ih;
        float uni = area_a + area_b - inter;
        float iou = inter / uni;
        float ex0 = fminf(px0, tx0), ey0 = fminf(py0, ty0);
        float ex1 = fmaxf(px1, tx1), ey1 = fmaxf(py1, ty1);
        float ew = fmaxf(ex1 - ex0, 0.f), eh = fmaxf(ey1 - ey0, 0.f);
        float encl = ew * eh;
        float giou = iou - (encl - uni) / encl;
        float cost_giou = 1.0f - giou;
        orow[j] = 5.0f*cost_bbox + cost_class + 2.0f*cost_giou;
    }
}

// ---------------- Hungarian (Jonker-Volgenant) kernel ----------------
// one block per batch; float64 state, op-order identical to the numpy ref.
#define LSA_THREADS 1024
#define LSA_WAVES (LSA_THREADS/64)

__global__ __launch_bounds__(LSA_THREADS) void lsa_kernel(
    const float* __restrict__ C3,
    float* __restrict__ outp, float* __restrict__ outt)
{
    int b = blockIdx.x;
    int tid = threadIdx.x;
    __shared__ double u[NT+1];
    __shared__ double v[NQ+1];
    __shared__ double minv[NQ+1];
    __shared__ int way[NQ+1];
    __shared__ int p[NQ+1];
    __shared__ unsigned char used[NQ+1];
    __shared__ double red_v[LSA_WAVES];
    __shared__ int red_i[LSA_WAVES];
    __shared__ double sh_delta;
    __shared__ int sh_j1, sh_j0, sh_i0;
    __shared__ int rows[NT];

    // cost[r][q] = C3[b, q, b*NT + r]  -> Cb[q*NJ + r]
    const float* Cb = C3 + (size_t)b * NQ * NJ + b * NT;

    for (int j = tid; j <= NQ; j += LSA_THREADS) { v[j] = 0.0; p[j] = 0; way[j] = 0; }
    if (tid <= NT) u[tid] = 0.0;
    __syncthreads();

    for (int i = 1; i <= NT; ++i) {
        for (int j = tid; j <= NQ; j += LSA_THREADS) { minv[j] = 1e18; used[j] = 0; }
        if (tid == 0) { p[0] = i; sh_j0 = 0; }
        __syncthreads();
        while (true) {
            if (tid == 0) { used[sh_j0] = 1; sh_i0 = p[sh_j0]; }
            __syncthreads();
            int i0 = sh_i0;
            int j0 = sh_j0;
            double cand = 1e18; int ci = 1 << 20;
            if (tid >= 1 && tid <= NQ && !used[tid]) {
                double cur = ((double)Cb[(size_t)(tid-1)*NJ + (i0-1)] - u[i0]) - v[tid];
                if (cur < minv[tid]) { minv[tid] = cur; way[tid] = j0; }
                cand = minv[tid];
                ci = tid;
            }
            // block argmin, first-index tie-break (matches np.argmin)
            for (int off = 32; off; off >>= 1) {
                double ov = __shfl_xor(cand, off);
                int    oi = __shfl_xor(ci, off);
                if (ov < cand || (ov == cand && oi < ci)) { cand = ov; ci = oi; }
            }
            int wv = tid >> 6;
            if ((tid & 63) == 0) { red_v[wv] = cand; red_i[wv] = ci; }
            __syncthreads();
            if (tid == 0) {
                double best = red_v[0]; int bi = red_i[0];
                for (int w = 1; w < LSA_WAVES; ++w)
                    if (red_v[w] < best || (red_v[w] == best && red_i[w] < bi)) { best = red_v[w]; bi = red_i[w]; }
                sh_delta = best; sh_j1 = bi;
            }
            __syncthreads();
            double delta = sh_delta; int j1 = sh_j1;
            if (tid <= NQ) {
                if (used[tid]) { v[tid] -= delta; u[p[tid]] += delta; }
                else if (tid >= 1) { minv[tid] -= delta; }
            }
            __syncthreads();
            if (tid == 0) sh_j0 = j1;
            __syncthreads();
            if (p[j1] == 0) break;
        }
        if (tid == 0) {
            int j0 = sh_j0;
            while (j0) { int jp = way[j0]; p[j0] = p[jp]; j0 = jp; }
        }
        __syncthreads();
    }
    // extract assignment: rows[target] = query
    if (tid >= 1 && tid <= NQ && p[tid] > 0) rows[p[tid]-1] = tid - 1;
    __syncthreads();
    if (tid == 0) {
        int pr[NT], tg[NT];
        for (int r = 0; r < NT; ++r) { pr[r] = rows[r]; tg[r] = r; }
        for (int a = 1; a < NT; ++a) {
            int kp = pr[a], kt = tg[a]; int bnd = a - 1;
            while (bnd >= 0 && pr[bnd] > kp) { pr[bnd+1] = pr[bnd]; tg[bnd+1] = tg[bnd]; --bnd; }
            pr[bnd+1] = kp; tg[bnd+1] = kt;
        }
        for (int k = 0; k < NT; ++k) {
            outp[b*NT + k] = (float)pr[k];
            outt[b*NT + k] = (float)tg[k];
        }
    }
}

extern "C" void kernel_launch(void* const* d_in, const int* in_sizes, int n_in,
                              void* d_out, int out_size, void* d_ws, size_t ws_size,
                              hipStream_t stream) {
    const float* logits  = (const float*)d_in[0];
    const float* pboxes  = (const float*)d_in[1];
    const int*   tlabels = (const int*)d_in[2];
    const float* tboxes  = (const float*)d_in[3];
    float* out = (float*)d_out;

    cost_kernel<<<BS*NQ, 256, 0, stream>>>(logits, pboxes, tlabels, tboxes, out);
    lsa_kernel<<<BS, LSA_THREADS, 0, stream>>>(out, out + C3_SZ, out + C3_SZ + BS*NT);
}

// Round 2
// 298.232 us; speedup vs baseline: 1.0692x; 1.0692x over previous
//
#include <hip/hip_runtime.h>
#include <hip/hip_bf16.h>
#include <math.h>

#define BS 32
#define NQ 900
#define NC 91
#define NT 30
#define NJ (BS*NT)            // 960
#define C3_SZ ((size_t)BS*NQ*NJ)
#define NROWS (BS*NQ)         // 28800

__device__ __forceinline__ float fast_rcp(float x) { return __builtin_amdgcn_rcpf(x); }

// ---------------- Cost matrix kernel ----------------
// 1024 threads: t<960 = persistent target columns, t>=960 = softmax wave
// computing the NEXT row's 91 class probs into a double-buffered LDS table.
__global__ __launch_bounds__(1024) void cost_kernel(
    const float* __restrict__ logits,   // (NROWS, NC)
    const float* __restrict__ pboxes,   // (NROWS, 4)
    const int*   __restrict__ tlabels,  // (NJ)
    const float* __restrict__ tboxes,   // (NJ, 4)
    float* __restrict__ out)            // (NROWS, NJ)
{
    __shared__ float prob[2][96];
    __shared__ float rowpar[2][12];     // pcx,pcy,pw,ph,px0,py0,px1,py1,area_a
    const int t = threadIdx.x;
    const int g = gridDim.x;
    const int r0 = (int)(((long long)blockIdx.x * NROWS) / g);
    const int r1 = (int)(((long long)(blockIdx.x + 1) * NROWS) / g);
    const int nrows = r1 - r0;

    // persistent per-target registers
    int   tl = 0;
    float tcx = 0, tcy = 0, tw = 0, th = 0, tx0 = 0, ty0 = 0, tx1 = 0, ty1 = 0, area_b = 0;
    if (t < NJ) {
        tl = tlabels[t];
        float4 tb = ((const float4*)tboxes)[t];
        tcx = tb.x; tcy = tb.y; tw = tb.z; th = tb.w;
        tx0 = tcx - 0.5f*tw; ty0 = tcy - 0.5f*th;
        tx1 = tcx + 0.5f*tw; ty1 = tcy + 0.5f*th;
        area_b = (tx1 - tx0) * (ty1 - ty0);
    }

    const int lane = t - NJ;            // softmax wave lane (valid when t>=960)

    // prologue: softmax wave fills buffer 0 with row r0
    if (t >= NJ) {
        int r = r0;
        const float* lrow = logits + (size_t)r * NC;
        float a  = (lane < NC)      ? lrow[lane]      : -1e30f;
        float c2 = (lane + 64 < NC) ? lrow[lane + 64] : -1e30f;
        float m = fmaxf(a, c2);
        for (int off = 32; off; off >>= 1) m = fmaxf(m, __shfl_xor(m, off));
        float ea = (lane < NC)      ? __expf(a - m)  : 0.f;
        float ec = (lane + 64 < NC) ? __expf(c2 - m) : 0.f;
        float s = ea + ec;
        for (int off = 32; off; off >>= 1) s += __shfl_xor(s, off);
        float rs = fast_rcp(s);
        if (lane < NC)      prob[0][lane]      = ea * rs;
        if (lane + 64 < NC) prob[0][lane + 64] = ec * rs;
        if (lane == 0) {
            float4 pb = ((const float4*)pboxes)[r];
            rowpar[0][0] = pb.x; rowpar[0][1] = pb.y; rowpar[0][2] = pb.z; rowpar[0][3] = pb.w;
            rowpar[0][4] = pb.x - 0.5f*pb.z; rowpar[0][5] = pb.y - 0.5f*pb.w;
            rowpar[0][6] = pb.x + 0.5f*pb.z; rowpar[0][7] = pb.y + 0.5f*pb.w;
            rowpar[0][8] = pb.z * pb.w;
        }
    }

    for (int k = 0; k < nrows; ++k) {
        __syncthreads();
        const int buf = k & 1;
        if (t >= NJ) {
            // compute row r0+k+1 into buffer buf^1
            if (k + 1 < nrows) {
                int r = r0 + k + 1;
                int nb = buf ^ 1;
                const float* lrow = logits + (size_t)r * NC;
                float a  = (lane < NC)      ? lrow[lane]      : -1e30f;
                float c2 = (lane + 64 < NC) ? lrow[lane + 64] : -1e30f;
                float m = fmaxf(a, c2);
                for (int off = 32; off; off >>= 1) m = fmaxf(m, __shfl_xor(m, off));
                float ea = (lane < NC)      ? __expf(a - m)  : 0.f;
                float ec = (lane + 64 < NC) ? __expf(c2 - m) : 0.f;
                float s = ea + ec;
                for (int off = 32; off; off >>= 1) s += __shfl_xor(s, off);
                float rs = fast_rcp(s);
                if (lane < NC)      prob[nb][lane]      = ea * rs;
                if (lane + 64 < NC) prob[nb][lane + 64] = ec * rs;
                if (lane == 0) {
                    float4 pb = ((const float4*)pboxes)[r];
                    rowpar[nb][0] = pb.x; rowpar[nb][1] = pb.y; rowpar[nb][2] = pb.z; rowpar[nb][3] = pb.w;
                    rowpar[nb][4] = pb.x - 0.5f*pb.z; rowpar[nb][5] = pb.y - 0.5f*pb.w;
                    rowpar[nb][6] = pb.x + 0.5f*pb.z; rowpar[nb][7] = pb.y + 0.5f*pb.w;
                    rowpar[nb][8] = pb.z * pb.w;
                }
            }
        } else {
            const int r = r0 + k;
            float pcx = rowpar[buf][0], pcy = rowpar[buf][1];
            float pw  = rowpar[buf][2], ph  = rowpar[buf][3];
            float px0 = rowpar[buf][4], py0 = rowpar[buf][5];
            float px1 = rowpar[buf][6], py1 = rowpar[buf][7];
            float area_a = rowpar[buf][8];
            float pr = prob[buf][tl];
            float cost_bbox = fabsf(pcx - tcx) + fabsf(pcy - tcy) + fabsf(pw - tw) + fabsf(ph - th);
            float ix0 = fmaxf(px0, tx0), iy0 = fmaxf(py0, ty0);
            float ix1 = fminf(px1, tx1), iy1 = fminf(py1, ty1);
            float inter = fmaxf(ix1 - ix0, 0.f) * fmaxf(iy1 - iy0, 0.f);
            float uni = area_a + area_b - inter;
            float iou = inter * fast_rcp(uni);
            float ex0 = fminf(px0, tx0), ey0 = fminf(py0, ty0);
            float ex1 = fmaxf(px1, tx1), ey1 = fmaxf(py1, ty1);
            float encl = fmaxf(ex1 - ex0, 0.f) * fmaxf(ey1 - ey0, 0.f);
            float giou = iou - (encl - uni) * fast_rcp(encl);
            // C = 5*bbox + (1-prob) + 2*(1-giou) = 5*bbox - prob - 2*giou + 3
            out[(size_t)r * NJ + t] = 5.0f*cost_bbox - pr - 2.0f*giou + 3.0f;
        }
    }
}

// ---------------- Hungarian (Jonker-Volgenant) kernel ----------------
// one block of 960 threads per batch. Cost submatrix staged in LDS.
// Thread t owns column t (t=0 is the virtual column 0). f64 state, exact
// numpy-reference op order. 2 barriers per Dijkstra iteration.
#define LT 960
#define LWAVES (LT/64)   // 15

__global__ __launch_bounds__(LT) void lsa_kernel(
    const float* __restrict__ C3,
    float* __restrict__ outp, float* __restrict__ outt)
{
    const int b = blockIdx.x;
    const int t = threadIdx.x;
    __shared__ float  cst[NT * NQ];          // 108 KB: cst[r*NQ+q]
    __shared__ double u_lds[NT + 1];
    __shared__ int    p_lds[NQ + 1];
    __shared__ int    way_lds[NQ + 1];
    __shared__ double red_v[LWAVES];
    __shared__ int    red_i[LWAVES];
    __shared__ int    rows_sh[NT];

    const float* Cb = C3 + (size_t)b * NQ * NJ + b * NT;
    // stage: k = q*NT + r  (global-contiguous chunks of 30) -> cst[r*NQ+q]
    for (int k = t; k < NT * NQ; k += LT) {
        int q = k / NT;
        int r = k - q * NT;
        cst[r * NQ + q] = Cb[(size_t)q * NJ + r];
    }
    for (int j = t; j <= NQ; j += LT) { p_lds[j] = 0; way_lds[j] = 0; }
    if (t <= NT) u_lds[t] = 0.0;
    double v_t = 0.0;
    __syncthreads();

    for (int i = 1; i <= NT; ++i) {
        double minv_t = 1e18;
        bool used_t = (t == 0);
        int p_t = (t == 0) ? i : ((t <= NQ) ? p_lds[t] : 0);
        int i0 = i, j0 = 0, j1f = 0;
        for (;;) {
            double u_i0 = u_lds[i0];
            double cand; int ci;
            if (t >= 1 && t <= NQ && !used_t) {
                double cur = ((double)cst[(i0 - 1) * NQ + (t - 1)] - u_i0) - v_t;
                if (cur < minv_t) { minv_t = cur; way_lds[t] = j0; }
                cand = minv_t; ci = t;
            } else { cand = 1e18; ci = 1 << 20; }
            // in-wave argmin (first-index tie-break)
            for (int off = 32; off; off >>= 1) {
                double ov = __shfl_xor(cand, off);
                int    oi = __shfl_xor(ci, off);
                if (ov < cand || (ov == cand && oi < ci)) { cand = ov; ci = oi; }
            }
            int wv = t >> 6;
            if ((t & 63) == 0) { red_v[wv] = cand; red_i[wv] = ci; }
            __syncthreads();                                   // (A)
            // every wave redundantly reduces the 15 per-wave results
            int ll = t & 63;
            double rv; int ri;
            if (ll < LWAVES) { rv = red_v[ll]; ri = red_i[ll]; }
            else             { rv = 1e18;      ri = 1 << 20;  }
            for (int off = 8; off; off >>= 1) {
                double ov = __shfl_xor(rv, off);
                int    oi = __shfl_xor(ri, off);
                if (ov < rv || (ov == rv && oi < ri)) { rv = ov; ri = oi; }
            }
            double delta = __shfl(rv, 0);
            int    j1    = __shfl(ri, 0);
            // updates (exact ref order: u/v for used, minv-delta for unused)
            if (used_t) { v_t -= delta; u_lds[p_t] += delta; }
            else if (t >= 1 && t <= NQ) minv_t -= delta;
            if (t == j1) used_t = true;
            int pj1 = p_lds[j1];
            __syncthreads();                                   // (B)
            if (pj1 == 0) { j1f = j1; break; }
            i0 = pj1; j0 = j1;
        }
        if (t == 0) {
            int j0w = j1f;
            while (j0w) {
                int jp = way_lds[j0w];
                p_lds[j0w] = (jp == 0) ? i : p_lds[jp];
                j0w = jp;
            }
        }
        __syncthreads();                                       // (C)
    }
    if (t >= 1 && t <= NQ && p_lds[t] > 0) rows_sh[p_lds[t] - 1] = t - 1;
    __syncthreads();
    if (t == 0) {
        int pr[NT], tg[NT];
        for (int r = 0; r < NT; ++r) { pr[r] = rows_sh[r]; tg[r] = r; }
        for (int a = 1; a < NT; ++a) {
            int kp = pr[a], kt = tg[a]; int bnd = a - 1;
            while (bnd >= 0 && pr[bnd] > kp) { pr[bnd+1] = pr[bnd]; tg[bnd+1] = tg[bnd]; --bnd; }
            pr[bnd+1] = kp; tg[bnd+1] = kt;
        }
        for (int k = 0; k < NT; ++k) {
            outp[b*NT + k] = (float)pr[k];
            outt[b*NT + k] = (float)tg[k];
        }
    }
}

extern "C" void kernel_launch(void* const* d_in, const int* in_sizes, int n_in,
                              void* d_out, int out_size, void* d_ws, size_t ws_size,
                              hipStream_t stream) {
    const float* logits  = (const float*)d_in[0];
    const float* pboxes  = (const float*)d_in[1];
    const int*   tlabels = (const int*)d_in[2];
    const float* tboxes  = (const float*)d_in[3];
    float* out = (float*)d_out;

    cost_kernel<<<512, 1024, 0, stream>>>(logits, pboxes, tlabels, tboxes, out);
    lsa_kernel<<<BS, LT, 0, stream>>>(out, out + C3_SZ, out + C3_SZ + (size_t)BS*NT);
}